// Round 4
// baseline (1632.480 us; speedup 1.0000x reference)
//
#include <hip/hip_runtime.h>

// SNN: T=200, B=256, IN=784, N=1024, OUT=10
// W_rec = -0.5*(ones - I) => prev@W_rec = -0.5*(S_b - prev[b,j])  (exact in
// fp32: all partial sums are multiples of 0.5 with |.| <= 512).
// net_in[t] = x_t @ W_in is time-independent => one big fp32 GEMM up front
// into d_out's hidden_spikes region, then an in-place spike scan.
//
// NUMERICS CONTRACT: dynamics are knife-edge (absmax 512 of 611 = one
// marginal spike-step flip vs BLAS summation order). The GEMM keeps a single
// ascending-k fmaf chain per output element — bit-identical across rounds.
// No MFMA/bf16, no split-K, no reassociation, true division in the scan.

#define TT 200
#define BB 256
#define KK 784
#define NN 1024
#define OO 10

#define FMA4(acc, s, v)                                                        \
  acc.x = fmaf(s, v.x, acc.x);                                                 \
  acc.y = fmaf(s, v.y, acc.y);                                                 \
  acc.z = fmaf(s, v.z, acc.z);                                                 \
  acc.w = fmaf(s, v.w, acc.w)

// ---------------- Phase 1: net = X(51200x784) @ W(784x1024), fp32 ----------
// 128x128 tile, BK=16, 256 threads, 8x8 micro-tile (2x2 quadrants of 4x4).
// Double-buffered LDS: ONE barrier per tile; LDS writes go to the idle
// buffer after compute (off the critical path); global loads for tile t+1
// are issued before the compute of tile t (latency hidden under 1024 FMAs).
__device__ __forceinline__ void compute_tile(const float (*__restrict__ A)[128],
                                             const float (*__restrict__ B)[128],
                                             float4 (&acc)[2][2][4], int tx,
                                             int ty) {
  const float4(*A4)[32] = (const float4(*)[32])A;
  const float4(*B4)[32] = (const float4(*)[32])B;
#pragma unroll
  for (int k = 0; k < 16; ++k) {
    float4 A0 = A4[k][ty];        // broadcast (free)
    float4 A1 = A4[k][16 + ty];
    float4 B0 = B4[k][tx];        // 2-way (free)
    float4 B1 = B4[k][16 + tx];
    FMA4(acc[0][0][0], A0.x, B0);
    FMA4(acc[0][1][0], A0.x, B1);
    FMA4(acc[0][0][1], A0.y, B0);
    FMA4(acc[0][1][1], A0.y, B1);
    FMA4(acc[0][0][2], A0.z, B0);
    FMA4(acc[0][1][2], A0.z, B1);
    FMA4(acc[0][0][3], A0.w, B0);
    FMA4(acc[0][1][3], A0.w, B1);
    FMA4(acc[1][0][0], A1.x, B0);
    FMA4(acc[1][1][0], A1.x, B1);
    FMA4(acc[1][0][1], A1.y, B0);
    FMA4(acc[1][1][1], A1.y, B1);
    FMA4(acc[1][0][2], A1.z, B0);
    FMA4(acc[1][1][2], A1.z, B1);
    FMA4(acc[1][0][3], A1.w, B0);
    FMA4(acc[1][1][3], A1.w, B1);
  }
}

__global__ __launch_bounds__(256)
void gemm_net(const float* __restrict__ X, const float* __restrict__ W,
              float* __restrict__ C) {
  __shared__ float As[2][16][128];   // [buf][k][m] (A staged transposed)
  __shared__ float Bs[2][16][128];   // [buf][k][n]

  const int tid = threadIdx.x;
  const int n0 = blockIdx.x * 128;
  const int m0 = blockIdx.y * 128;
  const int tx = tid & 15;             // cols tx*4, 64+tx*4
  const int ty = tid >> 4;             // rows ty*4, 64+ty*4
  const int arow = tid >> 1;           // 0..127
  const int ak   = (tid & 1) * 8;      // 0 or 8
  const int brow = tid >> 5;           // 0..7 (and +8)
  const int bc   = (tid & 31) * 4;     // 0..124

  const float* ap = X + (size_t)(m0 + arow) * KK + ak;
  const float* bp = W + (size_t)brow * NN + n0 + bc;

  float4 acc[2][2][4] = {};

  // stage tile 0 into buffer 0
  {
    float4 a0 = *(const float4*)(ap);
    float4 a1 = *(const float4*)(ap + 4);
    float4 b0 = *(const float4*)(bp);
    float4 b1 = *(const float4*)(bp + 8 * NN);
    As[0][ak + 0][arow] = a0.x;        // bank=arow%32, 2-way (free)
    As[0][ak + 1][arow] = a0.y;
    As[0][ak + 2][arow] = a0.z;
    As[0][ak + 3][arow] = a0.w;
    As[0][ak + 4][arow] = a1.x;
    As[0][ak + 5][arow] = a1.y;
    As[0][ak + 6][arow] = a1.z;
    As[0][ak + 7][arow] = a1.w;
    *(float4*)&Bs[0][brow][bc] = b0;   // lane-consecutive: conflict-free
    *(float4*)&Bs[0][brow + 8][bc] = b1;
  }
  __syncthreads();

  int p = 0;
  for (int t = 1; t < 49; ++t) {       // tiles 1..48
    // issue global loads for tile t (land during compute below)
    ap += 16;
    bp += 16 * NN;
    float4 a0 = *(const float4*)(ap);
    float4 a1 = *(const float4*)(ap + 4);
    float4 b0 = *(const float4*)(bp);
    float4 b1 = *(const float4*)(bp + 8 * NN);

    // compute tile t-1 from buffer p
    compute_tile(As[p], Bs[p], acc, tx, ty);

    // write tile t into buffer p^1 (no wave is reading p^1: barrier below
    // and the one from the previous iteration bracket it)
    const int q = p ^ 1;
    As[q][ak + 0][arow] = a0.x;
    As[q][ak + 1][arow] = a0.y;
    As[q][ak + 2][arow] = a0.z;
    As[q][ak + 3][arow] = a0.w;
    As[q][ak + 4][arow] = a1.x;
    As[q][ak + 5][arow] = a1.y;
    As[q][ak + 6][arow] = a1.z;
    As[q][ak + 7][arow] = a1.w;
    *(float4*)&Bs[q][brow][bc] = b0;
    *(float4*)&Bs[q][brow + 8][bc] = b1;
    __syncthreads();                   // the only barrier per tile
    p = q;
  }
  compute_tile(As[p], Bs[p], acc, tx, ty);   // tile 48

#pragma unroll
  for (int qi = 0; qi < 2; ++qi)
#pragma unroll
    for (int i = 0; i < 4; ++i) {
      const int r = m0 + qi * 64 + ty * 4 + i;
#pragma unroll
      for (int qj = 0; qj < 2; ++qj)
        *(float4*)(C + (size_t)r * NN + n0 + qj * 64 + tx * 4) =
            acc[qi][qj][i];
    }
}

// ---------------- Phase 2: sequential scan, one WAVE per batch row ---------
// 256 blocks x 64 threads: 16 neurons per lane, whole row in one wave.
// Row spike count S via 6-step shfl_xor butterfly (exact: integer-valued).
// ZERO barriers, zero LDS. Depth-2 register prefetch of net; t-loop
// unrolled x2 so the two prefetch buffers stay in registers.
__global__ __launch_bounds__(64)
void snn_scan(float* __restrict__ hid, const float* __restrict__ Wout,
              float* __restrict__ logits) {
  constexpr float V_REST = -65.0f, THRESH0 = -50.0f, TAU_M = 20.0f,
                  TAU_TH = 100.0f, BETA = 5.0f, DT = 1.0f;
  const int b = blockIdx.x;
  const int lane = threadIdx.x;
  const size_t base = (size_t)b * NN + (size_t)lane * 16;
  const size_t STEP = (size_t)BB * NN;

  float mp[16], th[16], prev[16], cnt[16];
#pragma unroll
  for (int i = 0; i < 16; ++i) {
    mp[i] = V_REST; th[i] = THRESH0; prev[i] = 0.0f; cnt[i] = 0.0f;
  }
  float S = 0.0f;

  float4 bufA[4], bufB[4];
#pragma unroll
  for (int q = 0; q < 4; ++q) bufA[q] = *(const float4*)&hid[base + 4 * q];
#pragma unroll
  for (int q = 0; q < 4; ++q)
    bufB[q] = *(const float4*)&hid[STEP + base + 4 * q];

#define NEURON(i, nval, sq)                                                    \
  {                                                                            \
    float rec = -0.5f * (S - prev[i]);                                         \
    float nv = nval + rec;                  /* np elementwise add order */     \
    float m = mp[i] + (V_REST - mp[i]) / TAU_M; /* true division */            \
    m = m + nv * DT;                                                           \
    bool spk = (m >= th[i]);                                                   \
    float s = spk ? 1.0f : 0.0f;                                               \
    th[i] = (th[i] + BETA * s) - ((th[i] - THRESH0) / TAU_TH) * DT;            \
    mp[i] = spk ? V_REST : m;                                                  \
    cnt[i] += s;                                                               \
    prev[i] = s;                                                               \
    sq = s;                                                                    \
    local += s;                                                                \
  }

#define SCAN_STEP(t, buf)                                                      \
  {                                                                            \
    float local = 0.0f;                                                        \
    float4 sp[4];                                                              \
    NEURON(0, buf[0].x, sp[0].x);                                              \
    NEURON(1, buf[0].y, sp[0].y);                                              \
    NEURON(2, buf[0].z, sp[0].z);                                              \
    NEURON(3, buf[0].w, sp[0].w);                                              \
    NEURON(4, buf[1].x, sp[1].x);                                              \
    NEURON(5, buf[1].y, sp[1].y);                                              \
    NEURON(6, buf[1].z, sp[1].z);                                              \
    NEURON(7, buf[1].w, sp[1].w);                                              \
    NEURON(8, buf[2].x, sp[2].x);                                              \
    NEURON(9, buf[2].y, sp[2].y);                                              \
    NEURON(10, buf[2].z, sp[2].z);                                             \
    NEURON(11, buf[2].w, sp[2].w);                                             \
    NEURON(12, buf[3].x, sp[3].x);                                             \
    NEURON(13, buf[3].y, sp[3].y);                                             \
    NEURON(14, buf[3].z, sp[3].z);                                             \
    NEURON(15, buf[3].w, sp[3].w);                                             \
    float* out = &hid[(size_t)(t)*STEP + base];                                \
    *(float4*)(out + 0) = sp[0];                                               \
    *(float4*)(out + 4) = sp[1];                                               \
    *(float4*)(out + 8) = sp[2];                                               \
    *(float4*)(out + 12) = sp[3];                                              \
    if ((t) + 2 < TT) {                                                        \
      const float* nx = &hid[(size_t)((t) + 2) * STEP + base];                 \
      buf[0] = *(const float4*)(nx + 0);                                       \
      buf[1] = *(const float4*)(nx + 4);                                       \
      buf[2] = *(const float4*)(nx + 8);                                       \
      buf[3] = *(const float4*)(nx + 12);                                      \
    }                                                                          \
    local += __shfl_xor(local, 1, 64);                                         \
    local += __shfl_xor(local, 2, 64);                                         \
    local += __shfl_xor(local, 4, 64);                                         \
    local += __shfl_xor(local, 8, 64);                                         \
    local += __shfl_xor(local, 16, 64);                                        \
    local += __shfl_xor(local, 32, 64);                                        \
    S = local; /* exact: sum of 0/1 ints */                                    \
  }

  for (int t = 0; t < TT; t += 2) {
    SCAN_STEP(t, bufA);
    SCAN_STEP(t + 1, bufB);
  }

  // logits[b,o] = sum_j cnt[b,j] * Wout[j,o]
  float lg[OO];
#pragma unroll
  for (int o = 0; o < OO; ++o) lg[o] = 0.0f;
#pragma unroll
  for (int i = 0; i < 16; ++i) {
    const float* wr = Wout + (size_t)(lane * 16 + i) * OO;
#pragma unroll
    for (int o = 0; o < OO; ++o) lg[o] = fmaf(cnt[i], wr[o], lg[o]);
  }
#pragma unroll
  for (int o = 0; o < OO; ++o) {
    lg[o] += __shfl_xor(lg[o], 1, 64);
    lg[o] += __shfl_xor(lg[o], 2, 64);
    lg[o] += __shfl_xor(lg[o], 4, 64);
    lg[o] += __shfl_xor(lg[o], 8, 64);
    lg[o] += __shfl_xor(lg[o], 16, 64);
    lg[o] += __shfl_xor(lg[o], 32, 64);
  }
  if (lane == 0) {
#pragma unroll
    for (int o = 0; o < OO; ++o) logits[(size_t)b * OO + o] = lg[o];
  }
}

extern "C" void kernel_launch(void* const* d_in, const int* in_sizes, int n_in,
                              void* d_out, int out_size, void* d_ws,
                              size_t ws_size, hipStream_t stream) {
  const float* X    = (const float*)d_in[0];  // input_spikes [200][256][784]
  const float* Win  = (const float*)d_in[1];  // [784][1024]
  // d_in[2] = W_rec — unused (exact closed form)
  const float* Wout = (const float*)d_in[3];  // [1024][10]

  float* logits = (float*)d_out;              // [256][10]
  float* hid    = (float*)d_out + BB * OO;    // [200][256][1024]

  dim3 g1(NN / 128, TT * BB / 128);           // 8 x 400 blocks
  gemm_net<<<g1, 256, 0, stream>>>(X, Win, hid);
  snn_scan<<<BB, 64, 0, stream>>>(hid, Wout, logits);
}

// Round 5
// 1538.536 us; speedup vs baseline: 1.0611x; 1.0611x over previous
//
#include <hip/hip_runtime.h>

// SNN: T=200, B=256, IN=784, N=1024, OUT=10
// W_rec = -0.5*(ones - I) => prev@W_rec = -0.5*(S_b - prev[b,j])  (exact in
// fp32: all partial sums are multiples of 0.5 with |.| <= 512).
// net_in[t] = x_t @ W_in is time-independent => one big fp32 GEMM up front
// into d_out's hidden_spikes region, then an in-place spike scan.
//
// NUMERICS CONTRACT: dynamics are knife-edge (absmax 512 of 611 = one
// marginal spike-step flip vs BLAS summation order; 2 flips would fail).
// The GEMM keeps a single ascending-k fmaf chain per output element —
// bit-identical across rounds. No MFMA/bf16, no split-K, no reassociation,
// true division in the scan.
//
// PERF MODEL (r4 post-mortem): 8x8 micro-tile reads 1 B LDS per FMA ->
// 41 GB LDS reads ~ 770 us at 85 B/cyc/CU vs 523 us FMA floor: rounds 2/3
// were LDS-read-bound. Fix: B operand bypasses LDS (W is 3 MB, L2-resident;
// 512 unique B bytes per k per block via L1). Hard constraints learned r4:
// VGPR <= 128 (occupancy bucket), keep TLP high.

#define TT 200
#define BB 256
#define KK 784
#define NN 1024
#define OO 10

#define FMA4(acc, s, v)                                                        \
  acc.x = fmaf(s, v.x, acc.x);                                                 \
  acc.y = fmaf(s, v.y, acc.y);                                                 \
  acc.z = fmaf(s, v.z, acc.z);                                                 \
  acc.w = fmaf(s, v.w, acc.w)

// ---------------- Phase 1: net = X(51200x784) @ W(784x1024), fp32 ----------
// 128x128 tile, BK=16, 256 threads, 8x8 micro-tile (2x2 quadrants of 4x4).
// A staged through LDS (transpose for coalescing), single 8 KB buffer,
// round-2's 2-barrier structure. B read directly from global (L1/L2-hot)
// with a depth-1 register pipeline.
__global__ __launch_bounds__(256)
void gemm_net(const float* __restrict__ X, const float* __restrict__ W,
              float* __restrict__ C) {
  __shared__ float As[16][128];   // [k][m] (A staged transposed), 8 KB
  float4 (*As4)[32] = (float4(*)[32])As;

  const int tid = threadIdx.x;
  const int n0 = blockIdx.x * 128;
  const int m0 = blockIdx.y * 128;
  const int tx = tid & 15;             // cols tx*4, 64+tx*4
  const int ty = tid >> 4;             // rows ty*4, 64+ty*4
  const int arow = tid >> 1;           // 0..127
  const int ak   = (tid & 1) * 8;      // 0 or 8

  const float* ap = X + (size_t)(m0 + arow) * KK + ak;

  float4 acc[2][2][4] = {};

  // preload A tile 0
  float4 a0 = *(const float4*)(ap);
  float4 a1 = *(const float4*)(ap + 4);

  for (int k0 = 0; k0 < KK; k0 += 16) {
    __syncthreads();                   // previous tile's LDS reads done
    As[ak + 0][arow] = a0.x;           // bank=arow%32, 2-way (free)
    As[ak + 1][arow] = a0.y;
    As[ak + 2][arow] = a0.z;
    As[ak + 3][arow] = a0.w;
    As[ak + 4][arow] = a1.x;
    As[ak + 5][arow] = a1.y;
    As[ak + 6][arow] = a1.z;
    As[ak + 7][arow] = a1.w;
    __syncthreads();

    // prefetch next A tile (lands during the ~2048-cyc inner loop)
    if (k0 + 16 < KK) {
      ap += 16;
      a0 = *(const float4*)(ap);
      a1 = *(const float4*)(ap + 4);
    }

    // inner loop: B from global, depth-1 register pipeline
    const float* wk = W + (size_t)k0 * NN + n0 + tx * 4;
    float4 B0c = *(const float4*)(wk);
    float4 B1c = *(const float4*)(wk + 64);
#pragma unroll
    for (int k = 0; k < 16; ++k) {
      float4 B0n, B1n;
      if (k < 15) {
        const float* wn = wk + NN;
        B0n = *(const float4*)(wn);
        B1n = *(const float4*)(wn + 64);
      }
      float4 A0 = As4[k][ty];          // broadcast (free)
      float4 A1 = As4[k][16 + ty];
      // one fmaf per acc element per k, ascending k: bit-exact contract
      FMA4(acc[0][0][0], A0.x, B0c);
      FMA4(acc[0][1][0], A0.x, B1c);
      FMA4(acc[0][0][1], A0.y, B0c);
      FMA4(acc[0][1][1], A0.y, B1c);
      FMA4(acc[0][0][2], A0.z, B0c);
      FMA4(acc[0][1][2], A0.z, B1c);
      FMA4(acc[0][0][3], A0.w, B0c);
      FMA4(acc[0][1][3], A0.w, B1c);
      FMA4(acc[1][0][0], A1.x, B0c);
      FMA4(acc[1][1][0], A1.x, B1c);
      FMA4(acc[1][0][1], A1.y, B0c);
      FMA4(acc[1][1][1], A1.y, B1c);
      FMA4(acc[1][0][2], A1.z, B0c);
      FMA4(acc[1][1][2], A1.z, B1c);
      FMA4(acc[1][0][3], A1.w, B0c);
      FMA4(acc[1][1][3], A1.w, B1c);
      if (k < 15) {
        B0c = B0n;
        B1c = B1n;
        wk += NN;
      }
    }
  }

#pragma unroll
  for (int qi = 0; qi < 2; ++qi)
#pragma unroll
    for (int i = 0; i < 4; ++i) {
      const int r = m0 + qi * 64 + ty * 4 + i;
#pragma unroll
      for (int qj = 0; qj < 2; ++qj)
        *(float4*)(C + (size_t)r * NN + n0 + qj * 64 + tx * 4) =
            acc[qi][qj][i];
    }
}

// ---------------- Phase 2: sequential scan, one WAVE per batch row ---------
// 256 blocks x 64 threads: 16 neurons per lane, whole row in one wave.
// Row spike count S via 16x ballot+popcount (exact integers, scalar-pipe
// adds — removes the ~700-cyc dependent shuffle chain of r4). Depth-4
// register prefetch of net covers L3 latency at 1 wave/CU.
__global__ __launch_bounds__(64)
void snn_scan(float* __restrict__ hid, const float* __restrict__ Wout,
              float* __restrict__ logits) {
  constexpr float V_REST = -65.0f, THRESH0 = -50.0f, TAU_M = 20.0f,
                  TAU_TH = 100.0f, BETA = 5.0f, DT = 1.0f;
  const int b = blockIdx.x;
  const int lane = threadIdx.x;
  const size_t base = (size_t)b * NN + (size_t)lane * 16;
  const size_t STEP = (size_t)BB * NN;

  float mp[16], th[16], prev[16], cnt[16];
#pragma unroll
  for (int i = 0; i < 16; ++i) {
    mp[i] = V_REST; th[i] = THRESH0; prev[i] = 0.0f; cnt[i] = 0.0f;
  }
  float S = 0.0f;

  float4 buf[4][4];                     // depth-4 net prefetch
#pragma unroll
  for (int d = 0; d < 4; ++d)
#pragma unroll
    for (int q = 0; q < 4; ++q)
      buf[d][q] = *(const float4*)&hid[(size_t)d * STEP + base + 4 * q];

#define NEURON(i, nval, sq)                                                    \
  {                                                                            \
    float rec = -0.5f * (S - prev[i]);                                         \
    float nv = nval + rec;                  /* np elementwise add order */     \
    float m = mp[i] + (V_REST - mp[i]) / TAU_M; /* true division */            \
    m = m + nv * DT;                                                           \
    bool spk = (m >= th[i]);                                                   \
    float s = spk ? 1.0f : 0.0f;                                               \
    th[i] = (th[i] + BETA * s) - ((th[i] - THRESH0) / TAU_TH) * DT;            \
    mp[i] = spk ? V_REST : m;                                                  \
    cnt[i] += s;                                                               \
    prev[i] = s;                                                               \
    sq = s;                                                                    \
    tot += __popcll(__ballot(spk));                                            \
  }

#define SCAN_STEP(t, d)                                                        \
  {                                                                            \
    int tot = 0;                                                               \
    float4 sp[4];                                                              \
    NEURON(0, buf[d][0].x, sp[0].x);                                           \
    NEURON(1, buf[d][0].y, sp[0].y);                                           \
    NEURON(2, buf[d][0].z, sp[0].z);                                           \
    NEURON(3, buf[d][0].w, sp[0].w);                                           \
    NEURON(4, buf[d][1].x, sp[1].x);                                           \
    NEURON(5, buf[d][1].y, sp[1].y);                                           \
    NEURON(6, buf[d][1].z, sp[1].z);                                           \
    NEURON(7, buf[d][1].w, sp[1].w);                                           \
    NEURON(8, buf[d][2].x, sp[2].x);                                           \
    NEURON(9, buf[d][2].y, sp[2].y);                                           \
    NEURON(10, buf[d][2].z, sp[2].z);                                          \
    NEURON(11, buf[d][2].w, sp[2].w);                                          \
    NEURON(12, buf[d][3].x, sp[3].x);                                          \
    NEURON(13, buf[d][3].y, sp[3].y);                                          \
    NEURON(14, buf[d][3].z, sp[3].z);                                          \
    NEURON(15, buf[d][3].w, sp[3].w);                                          \
    float* out = &hid[(size_t)(t)*STEP + base];                                \
    *(float4*)(out + 0) = sp[0];                                               \
    *(float4*)(out + 4) = sp[1];                                               \
    *(float4*)(out + 8) = sp[2];                                               \
    *(float4*)(out + 12) = sp[3];                                              \
    if ((t) + 4 < TT) {                                                        \
      const float* nx = &hid[(size_t)((t) + 4) * STEP + base];                 \
      buf[d][0] = *(const float4*)(nx + 0);                                    \
      buf[d][1] = *(const float4*)(nx + 4);                                    \
      buf[d][2] = *(const float4*)(nx + 8);                                    \
      buf[d][3] = *(const float4*)(nx + 12);                                   \
    }                                                                          \
    S = (float)tot; /* exact: popcount sum of 0/1 */                           \
  }

  for (int t = 0; t < TT; t += 4) {
    SCAN_STEP(t, 0);
    SCAN_STEP(t + 1, 1);
    SCAN_STEP(t + 2, 2);
    SCAN_STEP(t + 3, 3);
  }

  // logits[b,o] = sum_j cnt[b,j] * Wout[j,o]   (epilogue, off critical path)
  float lg[OO];
#pragma unroll
  for (int o = 0; o < OO; ++o) lg[o] = 0.0f;
#pragma unroll
  for (int i = 0; i < 16; ++i) {
    const float* wr = Wout + (size_t)(lane * 16 + i) * OO;
#pragma unroll
    for (int o = 0; o < OO; ++o) lg[o] = fmaf(cnt[i], wr[o], lg[o]);
  }
#pragma unroll
  for (int o = 0; o < OO; ++o) {
    lg[o] += __shfl_xor(lg[o], 1, 64);
    lg[o] += __shfl_xor(lg[o], 2, 64);
    lg[o] += __shfl_xor(lg[o], 4, 64);
    lg[o] += __shfl_xor(lg[o], 8, 64);
    lg[o] += __shfl_xor(lg[o], 16, 64);
    lg[o] += __shfl_xor(lg[o], 32, 64);
  }
  if (lane == 0) {
#pragma unroll
    for (int o = 0; o < OO; ++o) logits[(size_t)b * OO + o] = lg[o];
  }
}

extern "C" void kernel_launch(void* const* d_in, const int* in_sizes, int n_in,
                              void* d_out, int out_size, void* d_ws,
                              size_t ws_size, hipStream_t stream) {
  const float* X    = (const float*)d_in[0];  // input_spikes [200][256][784]
  const float* Win  = (const float*)d_in[1];  // [784][1024]
  // d_in[2] = W_rec — unused (exact closed form)
  const float* Wout = (const float*)d_in[3];  // [1024][10]

  float* logits = (float*)d_out;              // [256][10]
  float* hid    = (float*)d_out + BB * OO;    // [200][256][1024]

  dim3 g1(NN / 128, TT * BB / 128);           // 8 x 400 blocks
  gemm_net<<<g1, 256, 0, stream>>>(X, Win, hid);
  snn_scan<<<BB, 64, 0, stream>>>(hid, Wout, logits);
}